// Round 3
// baseline (417.496 us; speedup 1.0000x reference)
//
#include <hip/hip_runtime.h>
#include <math.h>

// SoftAttentionAggregator — MFMA fused kernel, round 3.
// B=8 H=256 P=1024 K=32 E=4 BN=64. One 256-thread block per (b, p-pair):
// GEMM hid[64 x 64] = W1[64x544] * Z[544x64], columns n = p_local*32 + k.
// nf staged via perfectly-coalesced dwordx4 loads (1KB/instr), bf16 c-pair
// packed in registers, XOR-swizzled LDS writes (conflict-free), b-frags as
// contiguous ds_read_b128. W1 pre-packed to bf16 A-frag layout in d_ws.

#define B_ 8
#define H_ 256
#define P_ 1024
#define K_ 32
#define E_ 4
#define BN_ 64

typedef __attribute__((ext_vector_type(8))) short short8;
typedef __attribute__((ext_vector_type(4))) float floatx4;

__device__ __forceinline__ unsigned short bf16_rne(float f) {
  unsigned u = __float_as_uint(f);
  u += 0x7fffu + ((u >> 16) & 1u);
  return (unsigned short)(u >> 16);
}
__device__ __forceinline__ unsigned pack_bf16_rne(float lo, float hi) {
  unsigned u0 = __float_as_uint(lo);
  u0 += 0x7fffu + ((u0 >> 16) & 1u);
  unsigned u1 = __float_as_uint(hi);
  u1 += 0x7fffu + ((u1 >> 16) & 1u);
  return (u0 >> 16) | (u1 & 0xffff0000u);
}

// Pack w1 (64x516) into bf16 MFMA A-frag layout:
// idx = ((mt*17 + ki)*64 + lane)*8 + j ; o = mt*16 + (lane&15),
// c = ki*32 + (lane>>4)*8 + j ; zero-pad c >= 516.
__global__ __launch_bounds__(256) void prep_kernel(
    const float* __restrict__ w1, unsigned short* __restrict__ w1m) {
  int i = blockIdx.x * 256 + threadIdx.x;
  if (i >= 4 * 17 * 64 * 8) return;  // 34816
  int j = i & 7, lane = (i >> 3) & 63;
  int kt = i >> 9;
  int mt = kt / 17, ki = kt % 17;
  int o = mt * 16 + (lane & 15);
  int c = ki * 32 + (lane >> 4) * 8 + j;
  float v = (c < 516) ? w1[o * 516 + c] : 0.f;
  w1m[i] = bf16_rne(v);
}

__global__ __launch_bounds__(256, 4) void soft_attn_agg_kernel(
    const float* __restrict__ cur,   // (B,H,P)
    const float* __restrict__ nf,    // (B,H,P,K)
    const float* __restrict__ nv,    // (B,1,P,K)
    const float* __restrict__ ef,    // (B,E,P,K)
    const unsigned short* __restrict__ w1m,  // packed A-frags
    const float* __restrict__ b1,    // (64)
    const float* __restrict__ w2,    // (64)
    float* __restrict__ out) {       // (B,H,P)
  // nf in LDS: bf16, row n (=pl*32+k) of 264 elems (132 dwords), c-pairs
  // packed in dwords, dword-quad XOR swizzle for bank-conflict-free writes.
  __shared__ unsigned s_nf_dw[BN_ * 132];          // 33792 B
  __shared__ __align__(16) unsigned short s_curb[2][H_];      // bf16 cur
  __shared__ __align__(16) unsigned short s_edgeT[2][K_][8];  // bf16 ef + pad
  __shared__ float s_valid[64];
  __shared__ __align__(16) float s_b1[BN_];
  __shared__ __align__(16) float s_w2[BN_];
  __shared__ float s_lg[BN_];
  __shared__ float s_wt[64];

  const int t = threadIdx.x;
  const unsigned bid = blockIdx.x;
  const unsigned xcd = bid & 7u, sidx = bid >> 3;       // sidx 0..511
  const int p0 = (int)(2u * (xcd * 64u + (sidx & 63u)));
  const int b = (int)(sidx >> 6);

  const int w = t >> 6;      // wave
  const int lane = t & 63;
  const int q = lane >> 4;   // quad
  const int ln15 = lane & 15;

  // ---- Phase 1: staging ----
  // nf: lane (r,s): r=lane>>4 row offset, s=lane&15 -> 16B chunk within the
  // 256B (2p x 32k) row. Each instr = 4 complete 256B segments (1KB).
  {
    const int r = lane >> 4, s = lane & 15;
    const float* base = nf + ((size_t)b * H_ * P_ + (size_t)p0) * K_;
    const int X = (s & 14) << 1;  // ((s>>1)&7)<<2 : dword-quad XOR swizzle
    unsigned* dst0 = s_nf_dw + (4 * s) * 132;
#pragma unroll
    for (int i = 0; i < 8; ++i) {
      const int c_even = w * 64 + i * 8 + 2 * r;
      const float4 fa = *(const float4*)(base + (size_t)c_even * (P_ * K_) + s * 4);
      const float4 fb = *(const float4*)(base + (size_t)(c_even + 1) * (P_ * K_) + s * 4);
      const int cp = (32 * w + 4 * i + r) ^ X;
      unsigned* dst = dst0 + cp;
      dst[0]   = pack_bf16_rne(fa.x, fb.x);
      dst[132] = pack_bf16_rne(fa.y, fb.y);
      dst[264] = pack_bf16_rne(fa.z, fb.z);
      dst[396] = pack_bf16_rne(fa.w, fb.w);
    }
  }
  // cur: 2 p's, thread t = channel c
  {
    const float* cp_ = cur + ((size_t)b * H_ + t) * P_ + p0;
    s_curb[0][t] = bf16_rne(cp_[0]);
    s_curb[1][t] = bf16_rne(cp_[1]);
  }
  if (t < 64) {
    // validity: contiguous 64 floats (2p x 32k)
    s_valid[t] = nv[((size_t)b * P_ + p0) * K_ + t];
    // edge: pl = t>>5, k = t&31
    const int pl = t >> 5, k = t & 31;
    const float* ep = ef + (((size_t)b * E_ * P_) + p0 + pl) * K_ + k;
    float e0 = ep[0];
    float e1 = ep[(size_t)P_ * K_];
    float e2 = ep[(size_t)(2 * P_) * K_];
    float e3 = ep[(size_t)(3 * P_) * K_];
    uint4 d;
    d.x = pack_bf16_rne(e0, e1);
    d.y = pack_bf16_rne(e2, e3);
    d.z = 0u; d.w = 0u;
    *(uint4*)&s_edgeT[pl][k][0] = d;
  } else if (t < 128) {
    s_b1[t - 64] = b1[t - 64];
  } else if (t < 192) {
    s_w2[t - 128] = w2[t - 128];
  }
  __syncthreads();

  // ---- Phase 2: GEMM. Wave w owns n-tile w (cols 16w..16w+15), loops mtiles.
  floatx4 acc[4];
#pragma unroll
  for (int mt = 0; mt < 4; ++mt)
    acc[mt] = *(const floatx4*)&s_b1[mt * 16 + q * 4];

  const int pl_w = w >> 1;  // wave's p_local (cols 16w..16w+15 within one p)
  const int n_lane = 16 * w + ln15;
  const int bxor = ((2 * w + (ln15 >> 3)) & 7) << 2;
  const unsigned* bsrc = s_nf_dw + n_lane * 132;
  const unsigned short* w1m_l = w1m + (size_t)lane * 8;

#pragma unroll
  for (int ki = 0; ki < 17; ++ki) {
    short8 bfrag;
    if (ki < 8) {
      bfrag = *(const short8*)&s_curb[pl_w][ki * 32 + q * 8];
    } else if (ki < 16) {
      bfrag = *(const short8*)(bsrc + ((16 * (ki - 8) + 4 * q) ^ bxor));
    } else {
      bfrag = *(const short8*)&s_edgeT[pl_w][(w & 1) * 16 + ln15][0];
    }
#pragma unroll
    for (int mt = 0; mt < 4; ++mt) {
      short8 a = *(const short8*)(w1m_l + (size_t)(mt * 17 + ki) * 512);
      acc[mt] = __builtin_amdgcn_mfma_f32_16x16x32_bf16(a, bfrag, acc[mt], 0, 0, 0);
    }
  }

  // ---- Phase 3: relu, dot w2, fold rows -> logit per column n
  {
    float lp = 0.f;
#pragma unroll
    for (int mt = 0; mt < 4; ++mt) {
      const floatx4 w2v = *(const floatx4*)&s_w2[mt * 16 + q * 4];
#pragma unroll
      for (int r = 0; r < 4; ++r)
        lp = fmaf(fmaxf(acc[mt][r], 0.f), w2v[r], lp);
    }
    lp += __shfl_xor(lp, 16);
    lp += __shfl_xor(lp, 32);
    if (lane < 16) s_lg[16 * w + lane] = lp;
  }
  __syncthreads();

  // ---- Phase 4: masked softmax per p over K=32 (threads 0..63 = wave 0)
  if (t < 64) {
    float lg = s_lg[t];
    bool v = s_valid[t] > 0.5f;
    float ml = v ? lg : -INFINITY;
#pragma unroll
    for (int m = 1; m < 32; m <<= 1) ml = fmaxf(ml, __shfl_xor(ml, m));
    float e = v ? __expf(lg - ml) : 0.f;
    float ssum = e;
#pragma unroll
    for (int m = 1; m < 32; m <<= 1) ssum += __shfl_xor(ssum, m);
    s_wt[t] = (ml > -INFINITY) ? (e / ssum) : 0.f;
  }
  __syncthreads();

  // ---- Phase 5: pooling. Thread t -> (pl = t>>7, c-pair = t&127).
  {
    const int pl = t >> 7, cpair = t & 127;
    float acc0 = 0.f, acc1 = 0.f;
#pragma unroll
    for (int k = 0; k < K_; ++k) {
      const int n = pl * 32 + k;
      const int xr = ((n >> 3) & 7) << 2;
      const unsigned u = s_nf_dw[n * 132 + (cpair ^ xr)];
      const float wtk = s_wt[n];
      acc0 = fmaf(__uint_as_float(u << 16), wtk, acc0);          // even c
      acc1 = fmaf(__uint_as_float(u & 0xffff0000u), wtk, acc1);  // odd c
    }
    float* op = out + ((size_t)b * H_ + 2 * cpair) * P_ + p0 + pl;
    op[0] = acc0;
    op[P_] = acc1;
  }
}

extern "C" void kernel_launch(void* const* d_in, const int* in_sizes, int n_in,
                              void* d_out, int out_size, void* d_ws,
                              size_t ws_size, hipStream_t stream) {
  const float* cur = (const float*)d_in[0];
  const float* nf  = (const float*)d_in[1];
  const float* nv  = (const float*)d_in[2];
  const float* ef  = (const float*)d_in[3];
  const float* w1  = (const float*)d_in[4];
  const float* b1  = (const float*)d_in[5];
  const float* w2  = (const float*)d_in[6];
  // d_in[7] = b2: softmax shift-invariant -> never affects output.

  unsigned short* w1m = (unsigned short*)d_ws;  // 34816 bf16 = 68 KB
  prep_kernel<<<(4 * 17 * 64 * 8 + 255) / 256, 256, 0, stream>>>(w1, w1m);
  soft_attn_agg_kernel<<<B_ * P_ / 2, 256, 0, stream>>>(
      cur, nf, nv, ef, w1m, b1, w2, (float*)d_out);
}

// Round 4
// 408.105 us; speedup vs baseline: 1.0230x; 1.0230x over previous
//
#include <hip/hip_runtime.h>
#include <math.h>

// SoftAttentionAggregator — MFMA fused kernel, round 4 ("BigP-8").
// B=8 H=256 P=1024 K=32 E=4 BN=64. One 512-thread block per (b, 8-p group):
// per-c-row global footprint = 8p*32k*4B = 1KB (full DRAM pages) vs 256B in r3.
// nf tile staged bf16 c-pair-packed in LDS rows n (132-dword stride, conflict-
// free), read once from HBM, reused for GEMM b-frags AND pooling.
// GEMM hid[64 x 256] = W1[64x544] * Z[544x256], cols n = pl*32+k, via
// mfma_f32_16x16x32_bf16; W1 pre-packed to A-frag layout in d_ws (L1-hot).

#define B_ 8
#define H_ 256
#define P_ 1024
#define K_ 32
#define E_ 4
#define BN_ 64

typedef __attribute__((ext_vector_type(8))) short short8;
typedef __attribute__((ext_vector_type(4))) float floatx4;

__device__ __forceinline__ unsigned short bf16_rne(float f) {
  unsigned u = __float_as_uint(f);
  u += 0x7fffu + ((u >> 16) & 1u);
  return (unsigned short)(u >> 16);
}
__device__ __forceinline__ unsigned pack_bf16_rne(float lo, float hi) {
  unsigned u0 = __float_as_uint(lo);
  u0 += 0x7fffu + ((u0 >> 16) & 1u);
  unsigned u1 = __float_as_uint(hi);
  u1 += 0x7fffu + ((u1 >> 16) & 1u);
  return (u0 >> 16) | (u1 & 0xffff0000u);
}

// Pack w1 (64x516) into bf16 MFMA A-frag layout:
// idx = ((mt*17 + ki)*64 + lane)*8 + j ; o = mt*16 + (lane&15),
// c = ki*32 + (lane>>4)*8 + j ; zero-pad c >= 516.
__global__ __launch_bounds__(256) void prep_kernel(
    const float* __restrict__ w1, unsigned short* __restrict__ w1m) {
  int i = blockIdx.x * 256 + threadIdx.x;
  if (i >= 4 * 17 * 64 * 8) return;  // 34816
  int j = i & 7, lane = (i >> 3) & 63;
  int kt = i >> 9;
  int mt = kt / 17, ki = kt % 17;
  int o = mt * 16 + (lane & 15);
  int c = ki * 32 + (lane >> 4) * 8 + j;
  float v = (c < 516) ? w1[o * 516 + c] : 0.f;
  w1m[i] = bf16_rne(v);
}

__global__ __launch_bounds__(512, 2) void soft_attn_agg_kernel(
    const float* __restrict__ cur,   // (B,H,P)
    const float* __restrict__ nf,    // (B,H,P,K)
    const float* __restrict__ nv,    // (B,1,P,K)
    const float* __restrict__ ef,    // (B,E,P,K)
    const unsigned short* __restrict__ w1m,  // packed A-frags
    const float* __restrict__ b1,    // (64)
    const float* __restrict__ w2,    // (64)
    float* __restrict__ out) {       // (B,H,P)
  // nf tile: 256 rows n (= pl*32+k), 128 c-pair dwords + 4 pad -> stride 132.
  __shared__ unsigned s_nf[256 * 132];          // 132 KB
  __shared__ unsigned short s_curb[8][264];     // bf16 cur [pl][c], 4.1 KB
  __shared__ unsigned s_edge[8][32][4];         // [pl][k][e01,e23,0,0], 4 KB
  __shared__ float s_valid[256];
  __shared__ float s_b1v[BN_];
  __shared__ float s_w2v[BN_];
  __shared__ float s_lg[256];
  __shared__ float s_wt[256];

  const int t = threadIdx.x;
  const unsigned bid = blockIdx.x;
  const unsigned xcd = bid & 7u, sx = bid >> 3;  // sx 0..127
  const int b = (int)(sx >> 4);
  const int pg = (int)(xcd * 16u + (sx & 15u));  // 0..127
  const int p0 = pg * 8;

  const int w = t >> 6;     // wave 0..7
  const int lane = t & 63;
  const int q = lane >> 4;  // quad
  const int ln15 = lane & 15;

  // ---- Phase 1: staging ----
  // nf: thread (n = t&255, ch = t>>8). Per instr: 64 lanes x 4B = 256B
  // contiguous (fixed c, consecutive n). Per c-row the BLOCK covers 1KB.
  {
    const int n = t & 255, ch = t >> 8;
    const float* gp = nf + (size_t)b * (H_ * P_ * K_) +
                      (size_t)(ch * 128) * (P_ * K_) + (size_t)p0 * K_ + n;
    unsigned* drow = s_nf + n * 132 + ch * 64;
#pragma unroll 4
    for (int i = 0; i < 16; ++i) {
      const float* gc = gp + (size_t)(8 * i) * (P_ * K_);
      float f0 = gc[0];
      float f1 = gc[(size_t)(P_ * K_)];
      float f2 = gc[(size_t)(2 * P_ * K_)];
      float f3 = gc[(size_t)(3 * P_ * K_)];
      float f4 = gc[(size_t)(4 * P_ * K_)];
      float f5 = gc[(size_t)(5 * P_ * K_)];
      float f6 = gc[(size_t)(6 * P_ * K_)];
      float f7 = gc[(size_t)(7 * P_ * K_)];
      uint4 d;
      d.x = pack_bf16_rne(f0, f1);
      d.y = pack_bf16_rne(f2, f3);
      d.z = pack_bf16_rne(f4, f5);
      d.w = pack_bf16_rne(f6, f7);
      *(uint4*)&drow[4 * i] = d;  // ds_write_b128, min-sweep
    }
  }
  if (t < 256) {
    // cur: 8 contiguous floats per c-row (c = t). Small volume (8KB/block).
    const float* cb = cur + ((size_t)b * H_ + t) * P_ + p0;
    float4 ca = *(const float4*)cb;
    float4 cc = *(const float4*)(cb + 4);
    s_curb[0][t] = bf16_rne(ca.x);
    s_curb[1][t] = bf16_rne(ca.y);
    s_curb[2][t] = bf16_rne(ca.z);
    s_curb[3][t] = bf16_rne(ca.w);
    s_curb[4][t] = bf16_rne(cc.x);
    s_curb[5][t] = bf16_rne(cc.y);
    s_curb[6][t] = bf16_rne(cc.z);
    s_curb[7][t] = bf16_rne(cc.w);
    // validity: 256 contiguous floats
    s_valid[t] = nv[((size_t)b * P_ + p0) * K_ + t];
    // edge: 4 rows of 256 contiguous floats; n-index = t = pl*32+k
    const int pl = t >> 5, k = t & 31;
    const float* ep = ef + (size_t)b * (E_ * P_ * K_) + (size_t)p0 * K_ + t;
    float e0 = ep[0];
    float e1 = ep[(size_t)(P_ * K_)];
    float e2 = ep[(size_t)(2 * P_ * K_)];
    float e3 = ep[(size_t)(3 * P_ * K_)];
    uint4 d;
    d.x = pack_bf16_rne(e0, e1);
    d.y = pack_bf16_rne(e2, e3);
    d.z = 0u;
    d.w = 0u;
    *(uint4*)&s_edge[pl][k][0] = d;
  } else if (t < 320) {
    s_b1v[t - 256] = b1[t - 256];
  } else if (t < 384) {
    s_w2v[t - 320] = w2[t - 320];
  }
  __syncthreads();

  // ---- Phase 2: GEMM. Wave w owns n-tiles {2w, 2w+1} (p_local = w), all mt.
  floatx4 acc[4][2];
#pragma unroll
  for (int mt = 0; mt < 4; ++mt) {
    floatx4 binit = *(const floatx4*)&s_b1v[mt * 16 + q * 4];
    acc[mt][0] = binit;
    acc[mt][1] = binit;
  }
  const unsigned short* w1m_l = w1m + (size_t)lane * 8;
  const int pl_w = w;

  // cur chunks (Z rows 0..255): b-frag independent of k -> shared by both nt
#pragma unroll
  for (int ki = 0; ki < 8; ++ki) {
    short8 bc = *(const short8*)&s_curb[pl_w][ki * 32 + q * 8];
#pragma unroll
    for (int mt = 0; mt < 4; ++mt) {
      short8 a = *(const short8*)(w1m_l + (size_t)(mt * 17 + ki) * 512);
      acc[mt][0] = __builtin_amdgcn_mfma_f32_16x16x32_bf16(a, bc, acc[mt][0], 0, 0, 0);
      acc[mt][1] = __builtin_amdgcn_mfma_f32_16x16x32_bf16(a, bc, acc[mt][1], 0, 0, 0);
    }
  }
  // nf chunks (Z rows 256..511)
#pragma unroll
  for (int ck = 0; ck < 8; ++ck) {
    short8 bn0 = *(const short8*)(s_nf + ((2 * w) * 16 + ln15) * 132 + 16 * ck + 4 * q);
    short8 bn1 = *(const short8*)(s_nf + ((2 * w + 1) * 16 + ln15) * 132 + 16 * ck + 4 * q);
#pragma unroll
    for (int mt = 0; mt < 4; ++mt) {
      short8 a = *(const short8*)(w1m_l + (size_t)(mt * 17 + 8 + ck) * 512);
      acc[mt][0] = __builtin_amdgcn_mfma_f32_16x16x32_bf16(a, bn0, acc[mt][0], 0, 0, 0);
      acc[mt][1] = __builtin_amdgcn_mfma_f32_16x16x32_bf16(a, bn1, acc[mt][1], 0, 0, 0);
    }
  }
  // edge chunk (Z rows 512..515; A rows >=516 are zero so B tail is don't-care)
  {
    short8 be0 = *(const short8*)&s_edge[pl_w][ln15][0];
    short8 be1 = *(const short8*)&s_edge[pl_w][16 + ln15][0];
#pragma unroll
    for (int mt = 0; mt < 4; ++mt) {
      short8 a = *(const short8*)(w1m_l + (size_t)(mt * 17 + 16) * 512);
      acc[mt][0] = __builtin_amdgcn_mfma_f32_16x16x32_bf16(a, be0, acc[mt][0], 0, 0, 0);
      acc[mt][1] = __builtin_amdgcn_mfma_f32_16x16x32_bf16(a, be1, acc[mt][1], 0, 0, 0);
    }
  }

  // ---- Phase 3: relu, dot w2, fold rows -> logit per column n
#pragma unroll
  for (int nti = 0; nti < 2; ++nti) {
    float lp = 0.f;
#pragma unroll
    for (int mt = 0; mt < 4; ++mt) {
      const floatx4 w2v = *(const floatx4*)&s_w2v[mt * 16 + q * 4];
#pragma unroll
      for (int r = 0; r < 4; ++r)
        lp = fmaf(fmaxf(acc[mt][nti][r], 0.f), w2v[r], lp);
    }
    lp += __shfl_xor(lp, 16);
    lp += __shfl_xor(lp, 32);
    if (lane < 16) s_lg[(2 * w + nti) * 16 + ln15] = lp;
  }
  __syncthreads();

  // ---- Phase 4: masked softmax per p over K=32 (threads 0..255, 2 p/wave)
  if (t < 256) {
    float lg = s_lg[t];
    bool v = s_valid[t] > 0.5f;
    float ml = v ? lg : -INFINITY;
#pragma unroll
    for (int m = 1; m < 32; m <<= 1) ml = fmaxf(ml, __shfl_xor(ml, m));
    float e = v ? __expf(lg - ml) : 0.f;
    float ssum = e;
#pragma unroll
    for (int m = 1; m < 32; m <<= 1) ssum += __shfl_xor(ssum, m);
    s_wt[t] = (ml > -INFINITY) ? (e / ssum) : 0.f;
  }
  __syncthreads();

  // ---- Phase 5: pooling. Thread t -> (cpr = t&127, p-pair ph = t>>7).
  {
    const int cpr = t & 127, ph = t >> 7;
    const int nb = ph * 64;  // n base for p = 2ph
    float a0e = 0.f, a0o = 0.f, a1e = 0.f, a1o = 0.f;
#pragma unroll
    for (int k = 0; k < K_; ++k) {
      const unsigned u0 = s_nf[(nb + k) * 132 + cpr];
      const unsigned u1 = s_nf[(nb + 32 + k) * 132 + cpr];
      const float wt0 = s_wt[nb + k];
      const float wt1 = s_wt[nb + 32 + k];
      a0e = fmaf(__uint_as_float(u0 << 16), wt0, a0e);
      a0o = fmaf(__uint_as_float(u0 & 0xffff0000u), wt0, a0o);
      a1e = fmaf(__uint_as_float(u1 << 16), wt1, a1e);
      a1o = fmaf(__uint_as_float(u1 & 0xffff0000u), wt1, a1o);
    }
    float* op = out + ((size_t)b * H_ + 2 * cpr) * P_ + p0 + 2 * ph;
    float2 ve; ve.x = a0e; ve.y = a1e;   // c even: p = 2ph, 2ph+1
    float2 vo; vo.x = a0o; vo.y = a1o;   // c odd
    *(float2*)op = ve;
    *(float2*)(op + P_) = vo;
  }
}

extern "C" void kernel_launch(void* const* d_in, const int* in_sizes, int n_in,
                              void* d_out, int out_size, void* d_ws,
                              size_t ws_size, hipStream_t stream) {
  const float* cur = (const float*)d_in[0];
  const float* nf  = (const float*)d_in[1];
  const float* nv  = (const float*)d_in[2];
  const float* ef  = (const float*)d_in[3];
  const float* w1  = (const float*)d_in[4];
  const float* b1  = (const float*)d_in[5];
  const float* w2  = (const float*)d_in[6];
  // d_in[7] = b2: softmax shift-invariant -> never affects output.

  unsigned short* w1m = (unsigned short*)d_ws;  // 34816 bf16 = 68 KB
  prep_kernel<<<(4 * 17 * 64 * 8 + 255) / 256, 256, 0, stream>>>(w1, w1m);
  soft_attn_agg_kernel<<<B_ * P_ / 8, 512, 0, stream>>>(
      cur, nf, nv, ef, w1m, b1, w2, (float*)d_out);
}

// Round 5
// 400.451 us; speedup vs baseline: 1.0426x; 1.0191x over previous
//
#include <hip/hip_runtime.h>
#include <math.h>

// SoftAttentionAggregator — round 5: async-DMA staging (global_load_lds).
// B=8 H=256 P=1024 K=32 E=4 BN=64. One 256-thread block per (b, 4-p group).
// nf staged RAW fp32 into a 16-c LDS chunk via __builtin_amdgcn_global_load_lds
// (width 4: per-lane global addr, LDS = uniform base + lane*4), then converted
// to a bf16 c-pair tile [n=pl*32+k][cp] (stride 132 dw). Rows/columns are
// wave-private across chunks -> 1 barrier per chunk, DMA of chunk i+1
// overlaps nothing within a block but the CU holds 2 blocks (80.9 KB LDS).
// GEMM hid[64 x 128] = W1[64x544] * Z[544x128] via mfma_f32_16x16x32_bf16.

#define B_ 8
#define H_ 256
#define P_ 1024
#define K_ 32
#define E_ 4
#define BN_ 64

typedef __attribute__((ext_vector_type(8))) short short8;
typedef __attribute__((ext_vector_type(4))) float floatx4;

__device__ __forceinline__ unsigned short bf16_rne(float f) {
  unsigned u = __float_as_uint(f);
  u += 0x7fffu + ((u >> 16) & 1u);
  return (unsigned short)(u >> 16);
}
__device__ __forceinline__ unsigned pack_bf16_rne(float lo, float hi) {
  unsigned u0 = __float_as_uint(lo);
  u0 += 0x7fffu + ((u0 >> 16) & 1u);
  unsigned u1 = __float_as_uint(hi);
  u1 += 0x7fffu + ((u1 >> 16) & 1u);
  return (u0 >> 16) | (u1 & 0xffff0000u);
}

// async global->LDS, 4 B per lane: lane i reads g[i-th lane's addr], LDS gets
// uniform base + lane*4. g must be per-lane (base + lane), l wave-uniform.
__device__ __forceinline__ void async_cp4(const float* g, float* l) {
  __builtin_amdgcn_global_load_lds(
      (const __attribute__((address_space(1))) unsigned*)g,
      (__attribute__((address_space(3))) unsigned*)l, 4, 0, 0);
}

// Pack w1 (64x516) into bf16 MFMA A-frag layout:
// idx = ((mt*17 + ki)*64 + lane)*8 + j ; o = mt*16 + (lane&15),
// c = ki*32 + (lane>>4)*8 + j ; zero-pad c >= 516.
__global__ __launch_bounds__(256) void prep_kernel(
    const float* __restrict__ w1, unsigned short* __restrict__ w1m) {
  int i = blockIdx.x * 256 + threadIdx.x;
  if (i >= 4 * 17 * 64 * 8) return;  // 34816
  int j = i & 7, lane = (i >> 3) & 63;
  int kt = i >> 9;
  int mt = kt / 17, ki = kt % 17;
  int o = mt * 16 + (lane & 15);
  int c = ki * 32 + (lane >> 4) * 8 + j;
  float v = (c < 516) ? w1[o * 516 + c] : 0.f;
  w1m[i] = bf16_rne(v);
}

__global__ __launch_bounds__(256, 2) void soft_attn_agg_kernel(
    const float* __restrict__ cur,   // (B,H,P)
    const float* __restrict__ nf,    // (B,H,P,K)
    const float* __restrict__ nv,    // (B,1,P,K)
    const float* __restrict__ ef,    // (B,E,P,K)
    const unsigned short* __restrict__ w1m,  // packed A-frags (68 KB, L2-hot)
    const float* __restrict__ b1,    // (64)
    const float* __restrict__ w2,    // (64)
    float* __restrict__ out) {       // (B,H,P)
  __shared__ unsigned s_tile[128 * 132];       // bf16 c-pairs [n][cp], 67.6 KB
  __shared__ float s_raw[16 * 128];            // fp32 DMA chunk [c_loc][n], 8 KB
  __shared__ unsigned short s_curb[4][264];    // bf16 cur [pl][c]
  __shared__ unsigned s_edge[4][32][2];        // [pl][k][e01,e23]
  __shared__ float s_valid[128];
  __shared__ float s_b1v[BN_];
  __shared__ float s_w2v[BN_];
  __shared__ float s_lg[128];
  __shared__ float s_wt[128];

  const int t = threadIdx.x;
  const unsigned bid = blockIdx.x;
  const unsigned xcd = bid & 7u, sx = bid >> 3;  // sx 0..255
  const int b = (int)(sx >> 5);
  const int pg = (int)(xcd * 32u + (sx & 31u));  // 0..255
  const int p0 = pg * 4;

  const int w = t >> 6;     // wave 0..3
  const int lane = t & 63;
  const int q = lane >> 4;  // quad
  const int ln15 = lane & 15;

  // ---- small staging (normal loads; drained by the first chunk barrier) ----
  {
    const float* cb = cur + ((size_t)b * H_ + t) * P_ + p0;
    float4 ca = *(const float4*)cb;
    s_curb[0][t] = bf16_rne(ca.x);
    s_curb[1][t] = bf16_rne(ca.y);
    s_curb[2][t] = bf16_rne(ca.z);
    s_curb[3][t] = bf16_rne(ca.w);
  }
  if (t < 128) {
    s_valid[t] = nv[((size_t)b * P_ + p0) * K_ + t];
    const int pl = t >> 5, k = t & 31;
    const float* ep = ef + ((size_t)b * E_ * P_ + p0 + pl) * K_ + k;
    float e0 = ep[0];
    float e1 = ep[(size_t)(P_ * K_)];
    float e2 = ep[(size_t)(2 * P_ * K_)];
    float e3 = ep[(size_t)(3 * P_ * K_)];
    s_edge[pl][k][0] = pack_bf16_rne(e0, e1);
    s_edge[pl][k][1] = pack_bf16_rne(e2, e3);
  } else if (t < 192) {
    s_b1v[t - 128] = b1[t - 128];
  } else {
    s_w2v[t - 192] = w2[t - 192];
  }

  // ---- Phase 1: nf staging, 16 chunks of 16 c. Wave w owns c_loc 4w..4w+3
  // (DMA) and converts c-pairs {2w, 2w+1} of each chunk -> rows/cols are
  // wave-private; one barrier per chunk (drains own DMA vmcnt).
  const float* nf_b = nf + ((size_t)b * H_ * P_ + p0) * K_;
  for (int ch = 0; ch < 16; ++ch) {
#pragma unroll
    for (int r = 0; r < 4; ++r) {
      const int cl = 4 * w + r;
      const float* g = nf_b + (size_t)(ch * 16 + cl) * (P_ * K_);
      float* l = &s_raw[cl * 128];
      async_cp4(g + lane, l);
      async_cp4(g + 64 + lane, l + 64);
    }
    __syncthreads();  // s_waitcnt vmcnt(0) + barrier: raw chunk resident
#pragma unroll
    for (int j = 0; j < 2; ++j) {
      const int r0 = 4 * w + 2 * j;
      const int cp = ch * 8 + 2 * w + j;
#pragma unroll
      for (int i = 0; i < 2; ++i) {
        const int n = lane + 64 * i;
        float fe = s_raw[r0 * 128 + n];        // even c
        float fo = s_raw[(r0 + 1) * 128 + n];  // odd c
        s_tile[n * 132 + cp] = pack_bf16_rne(fe, fo);
      }
    }
    // no second barrier: next chunk's DMA only touches this wave's own rows
  }
  __syncthreads();  // tile complete for all waves

  // ---- Phase 2: GEMM. Wave w owns n-tiles {2w, 2w+1} (p_local = w), all mt.
  floatx4 acc[4][2];
#pragma unroll
  for (int mt = 0; mt < 4; ++mt) {
    floatx4 binit = *(const floatx4*)&s_b1v[mt * 16 + q * 4];
    acc[mt][0] = binit;
    acc[mt][1] = binit;
  }
  const unsigned short* w1m_l = w1m + (size_t)lane * 8;

  // cur chunks (Z rows 0..255): b-frag independent of k -> shared by both nt
#pragma unroll
  for (int ki = 0; ki < 8; ++ki) {
    short8 bc = *(const short8*)&s_curb[w][ki * 32 + q * 8];
#pragma unroll
    for (int mt = 0; mt < 4; ++mt) {
      short8 a = *(const short8*)(w1m_l + (size_t)(mt * 17 + ki) * 512);
      acc[mt][0] = __builtin_amdgcn_mfma_f32_16x16x32_bf16(a, bc, acc[mt][0], 0, 0, 0);
      acc[mt][1] = __builtin_amdgcn_mfma_f32_16x16x32_bf16(a, bc, acc[mt][1], 0, 0, 0);
    }
  }
  // nf chunks (Z rows 256..511): frag = tile[n][16ck+4q .. +3] (b128, 2-way)
#pragma unroll
  for (int ck = 0; ck < 8; ++ck) {
    short8 bn0 = *(const short8*)(s_tile + (32 * w + ln15) * 132 + 16 * ck + 4 * q);
    short8 bn1 = *(const short8*)(s_tile + (32 * w + 16 + ln15) * 132 + 16 * ck + 4 * q);
#pragma unroll
    for (int mt = 0; mt < 4; ++mt) {
      short8 a = *(const short8*)(w1m_l + (size_t)(mt * 17 + 8 + ck) * 512);
      acc[mt][0] = __builtin_amdgcn_mfma_f32_16x16x32_bf16(a, bn0, acc[mt][0], 0, 0, 0);
      acc[mt][1] = __builtin_amdgcn_mfma_f32_16x16x32_bf16(a, bn1, acc[mt][1], 0, 0, 0);
    }
  }
  // edge chunk (Z rows 512..515; A rows >=516 are zero -> B tail don't-care)
  {
    union { unsigned u[4]; short8 s; } ub0, ub1;
    *(uint2*)&ub0.u[0] = *(const uint2*)&s_edge[w][ln15][0];
    ub0.u[2] = 0u; ub0.u[3] = 0u;
    *(uint2*)&ub1.u[0] = *(const uint2*)&s_edge[w][16 + ln15][0];
    ub1.u[2] = 0u; ub1.u[3] = 0u;
#pragma unroll
    for (int mt = 0; mt < 4; ++mt) {
      short8 a = *(const short8*)(w1m_l + (size_t)(mt * 17 + 16) * 512);
      acc[mt][0] = __builtin_amdgcn_mfma_f32_16x16x32_bf16(a, ub0.s, acc[mt][0], 0, 0, 0);
      acc[mt][1] = __builtin_amdgcn_mfma_f32_16x16x32_bf16(a, ub1.s, acc[mt][1], 0, 0, 0);
    }
  }

  // ---- Phase 3: relu, dot w2, fold rows -> logit per column n
#pragma unroll
  for (int nti = 0; nti < 2; ++nti) {
    float lp = 0.f;
#pragma unroll
    for (int mt = 0; mt < 4; ++mt) {
      const floatx4 w2v = *(const floatx4*)&s_w2v[mt * 16 + q * 4];
#pragma unroll
      for (int r = 0; r < 4; ++r)
        lp = fmaf(fmaxf(acc[mt][nti][r], 0.f), w2v[r], lp);
    }
    lp += __shfl_xor(lp, 16);
    lp += __shfl_xor(lp, 32);
    if (lane < 16) s_lg[(2 * w + nti) * 16 + ln15] = lp;
  }
  __syncthreads();

  // ---- Phase 4: masked softmax per p over K=32 (threads 0..127)
  if (t < 128) {
    float lg = s_lg[t];
    bool v = s_valid[t] > 0.5f;
    float ml = v ? lg : -INFINITY;
#pragma unroll
    for (int m = 1; m < 32; m <<= 1) ml = fmaxf(ml, __shfl_xor(ml, m));
    float e = v ? __expf(lg - ml) : 0.f;
    float ssum = e;
#pragma unroll
    for (int m = 1; m < 32; m <<= 1) ssum += __shfl_xor(ssum, m);
    s_wt[t] = (ml > -INFINITY) ? (e / ssum) : 0.f;
  }
  __syncthreads();

  // ---- Phase 5: pooling. Thread t -> (cpr = t&127, p-pair ph = t>>7).
  {
    const int cpr = t & 127, ph = t >> 7;
    const int nb = ph * 64;  // n base for p_local = 2ph
    float a0e = 0.f, a0o = 0.f, a1e = 0.f, a1o = 0.f;
#pragma unroll
    for (int k = 0; k < K_; ++k) {
      const unsigned u0 = s_tile[(nb + k) * 132 + cpr];
      const unsigned u1 = s_tile[(nb + 32 + k) * 132 + cpr];
      const float wt0 = s_wt[nb + k];
      const float wt1 = s_wt[nb + 32 + k];
      a0e = fmaf(__uint_as_float(u0 << 16), wt0, a0e);
      a0o = fmaf(__uint_as_float(u0 & 0xffff0000u), wt0, a0o);
      a1e = fmaf(__uint_as_float(u1 << 16), wt1, a1e);
      a1o = fmaf(__uint_as_float(u1 & 0xffff0000u), wt1, a1o);
    }
    float* op = out + ((size_t)b * H_ + 2 * cpr) * P_ + p0 + 2 * ph;
    float2 ve; ve.x = a0e; ve.y = a1e;   // c even: p_local = 2ph, 2ph+1
    float2 vo; vo.x = a0o; vo.y = a1o;   // c odd
    *(float2*)op = ve;
    *(float2*)(op + P_) = vo;
  }
}

extern "C" void kernel_launch(void* const* d_in, const int* in_sizes, int n_in,
                              void* d_out, int out_size, void* d_ws,
                              size_t ws_size, hipStream_t stream) {
  const float* cur = (const float*)d_in[0];
  const float* nf  = (const float*)d_in[1];
  const float* nv  = (const float*)d_in[2];
  const float* ef  = (const float*)d_in[3];
  const float* w1  = (const float*)d_in[4];
  const float* b1  = (const float*)d_in[5];
  const float* w2  = (const float*)d_in[6];
  // d_in[7] = b2: softmax shift-invariant -> never affects output.

  unsigned short* w1m = (unsigned short*)d_ws;  // 34816 bf16 = 68 KB
  prep_kernel<<<(4 * 17 * 64 * 8 + 255) / 256, 256, 0, stream>>>(w1, w1m);
  soft_attn_agg_kernel<<<B_ * P_ / 4, 256, 0, stream>>>(
      cur, nf, nv, ef, w1m, b1, w2, (float*)d_out);
}